// Round 8
// baseline (603.470 us; speedup 1.0000x reference)
//
#include <hip/hip_runtime.h>
#include <hip/hip_bf16.h>

// okl = log_C_kappa + kappa + mean_j log( sum_i exp(kappa*<mu_n_i,z_j> - kappa) )
//       - log(M) - log_C_zero
// M = 2048 components, J = 65536 sample columns, d = 32.
//
// Schraudolph epilogue: A pre-scaled by kappa*log2e*2^23; MFMA C-operand holds
// (BIAS-S)*2^23 + MAGIC so int-truncation of the MFMA output is the IEEE bit
// pattern of 2^(score-S+BIAS). Per element: v_max, v_cvt_i32, v_add.
//
// R8 DIAGNOSTIC: all 16 A-frags loaded upfront (one latency exposure, then
// zero memory ops), MFMA+epilogue sweep run TWICE (acc exactly doubles,
// halved before log). 2x work pushes main into rocprof top-5 for real
// counters. A/B: if memory-latency was the stall, main_2x ~ 2x compute
// floor (~13us); if clock/issue-bound, ~50us.

typedef __attribute__((ext_vector_type(8))) short bf16x8;
typedef __attribute__((ext_vector_type(4))) float f32x4;

#define LOG2E 1.44269504088896340736
#define LN2 0.6931471805599453
#define BIAS 48.0
// 127*2^23 - D, D = 471400 (mean-log-centered linear-mantissa exp2)
#define MAGIC 1064881816.0
#define CLAMPF 8388608.0f   // 2^23: result exponent floor -> 2^-126, no wrap

static __device__ __forceinline__ unsigned short f2bf(float f) {
  unsigned int u = __float_as_uint(f);
  u += 0x7FFFu + ((u >> 16) & 1u);   // round-to-nearest-even
  return (unsigned short)(u >> 16);
}

// Kernel 1: Abf = bf16(kappa*log2e*2^23 * mu / ||mu||), 8 lanes per row.
// Thread (0,0) also writes out[0] = all-constant part of okl.
__global__ __launch_bounds__(256) void vmf_prep(const float* __restrict__ mu,
                                                const float* __restrict__ kp,
                                                const float* __restrict__ lck,
                                                const float* __restrict__ lc0,
                                                unsigned short* __restrict__ Abf,
                                                float* __restrict__ out, int M) {
  int tid = blockIdx.x * 256 + threadIdx.x;
  if (tid == 0) {
    out[0] = (float)((double)lck[0] + (double)kp[0] - BIAS * LN2 -
                     log((double)M) - (double)lc0[0]);
  }
  int row = tid >> 3;
  int sub = tid & 7;                  // 4 columns per lane
  if (row >= M) return;
  const float4 v = *(const float4*)(mu + (size_t)row * 32 + sub * 4);
  float ss = v.x * v.x + v.y * v.y + v.z * v.z + v.w * v.w;
  ss += __shfl_xor(ss, 1);
  ss += __shfl_xor(ss, 2);
  ss += __shfl_xor(ss, 4);            // full row norm within 8-lane group
  float sc = (float)((double)kp[0] * LOG2E * 8388608.0) / sqrtf(ss);
  ushort4 o;
  o.x = f2bf(v.x * sc); o.y = f2bf(v.y * sc);
  o.z = f2bf(v.z * sc); o.w = f2bf(v.w * sc);
  *(ushort4*)(Abf + (size_t)row * 32 + sub * 4) = o;
}

// Kernel 2 (M == 2048): block = 128 cols (8 N-tiles) x 8 waves, wave covers
// 256 rows = 16 A-frags, ALL loaded upfront. Two identical compute passes
// (diagnostic 2x work); acc exactly doubles, halved before log.
__global__ __launch_bounds__(512) void vmf_main(const unsigned short* __restrict__ Abf,
                                                const float* __restrict__ z,
                                                const float* __restrict__ kp,
                                                float* __restrict__ out, int J) {
  const int lane = threadIdx.x & 63;
  const int wave = threadIdx.x >> 6;   // 0..7
  const int r = lane & 15;
  const int q = lane >> 4;
  const float ci = (float)((BIAS - (double)kp[0] * LOG2E) * 8388608.0 + MAGIC);
  const f32x4 cinit = {ci, ci, ci, ci};
  const int colbase = blockIdx.x * 128;

  // All 16 A fragments upfront: 16 independent loads in flight.
  const unsigned short* ap = Abf + (size_t)(wave * 256 + r) * 32 + q * 8;
  bf16x8 a[16];
#pragma unroll
  for (int f = 0; f < 16; ++f)
    a[f] = *(const bf16x8*)(ap + (size_t)(f * 16) * 32);

  // Loop-invariant B fragments (8 tiles), fp32 -> bf16 on the fly.
  bf16x8 b[8];
#pragma unroll
  for (int t = 0; t < 8; ++t) {
    const float* zp = z + (size_t)(colbase + t * 16 + r) * 32 + q * 8;
    float4 fa = *(const float4*)zp;
    float4 fb = *(const float4*)(zp + 4);
    b[t][0] = (short)f2bf(fa.x); b[t][1] = (short)f2bf(fa.y);
    b[t][2] = (short)f2bf(fa.z); b[t][3] = (short)f2bf(fa.w);
    b[t][4] = (short)f2bf(fb.x); b[t][5] = (short)f2bf(fb.y);
    b[t][6] = (short)f2bf(fb.z); b[t][7] = (short)f2bf(fb.w);
  }

  float acc[8] = {0.f, 0.f, 0.f, 0.f, 0.f, 0.f, 0.f, 0.f};
#pragma unroll
  for (int p = 0; p < 2; ++p) {        // TWO passes (diagnostic)
#pragma unroll
    for (int f = 0; f < 16; ++f) {
#pragma unroll
      for (int t = 0; t < 8; ++t) {
        f32x4 c = __builtin_amdgcn_mfma_f32_16x16x32_bf16(a[f], b[t], cinit, 0, 0, 0);
#pragma unroll
        for (int e = 0; e < 4; ++e) {
          float cf = fmaxf(c[e], CLAMPF);
          acc[t] += __int_as_float((int)cf);   // Schraudolph exp2
        }
      }
    }
  }

  // Sum the 4 row-quadrants per column (lanes l, l^16, l^32, l^48 share col).
#pragma unroll
  for (int t = 0; t < 8; ++t) {
    acc[t] += __shfl_xor(acc[t], 16);
    acc[t] += __shfl_xor(acc[t], 32);
  }
  float vlo = (q == 0) ? acc[0] : (q == 1) ? acc[1] : (q == 2) ? acc[2] : acc[3];
  float vhi = (q == 0) ? acc[4] : (q == 1) ? acc[5] : (q == 2) ? acc[6] : acc[7];

  __shared__ float rlo[8][64];
  __shared__ float rhi[8][64];
  rlo[wave][lane] = vlo;
  rhi[wave][lane] = vhi;
  __syncthreads();

  if (wave == 0) {
    float slo = 0.f, shi = 0.f;
#pragma unroll
    for (int w = 0; w < 8; ++w) { slo += rlo[w][lane]; shi += rhi[w][lane]; }
    slo = fmaxf(slo * 0.5f, 1e-38f);   // undo the 2x from the double pass
    shi = fmaxf(shi * 0.5f, 1e-38f);
    float t = __logf(slo) + __logf(shi);   // 2 columns' t_j for this lane
    t += __shfl_xor(t, 1);  t += __shfl_xor(t, 2);
    t += __shfl_xor(t, 4);  t += __shfl_xor(t, 8);
    t += __shfl_xor(t, 16); t += __shfl_xor(t, 32);
    if (lane == 0) atomicAdd(out, t / (float)J);
  }
}

// Generic fallback (any M multiple of 16): single-pass loop.
__global__ __launch_bounds__(512) void vmf_main_gen(const unsigned short* __restrict__ Abf,
                                                    const float* __restrict__ z,
                                                    const float* __restrict__ kp,
                                                    float* __restrict__ out,
                                                    int M, int J) {
  const int lane = threadIdx.x & 63;
  const int wave = threadIdx.x >> 6;
  const int r = lane & 15;
  const int q = lane >> 4;
  const float ci = (float)((BIAS - (double)kp[0] * LOG2E) * 8388608.0 + MAGIC);
  const f32x4 cinit = {ci, ci, ci, ci};
  const int colbase = blockIdx.x * 128;

  bf16x8 b[8];
#pragma unroll
  for (int t = 0; t < 8; ++t) {
    const float* zp = z + (size_t)(colbase + t * 16 + r) * 32 + q * 8;
    float4 fa = *(const float4*)zp;
    float4 fb = *(const float4*)(zp + 4);
    b[t][0] = (short)f2bf(fa.x); b[t][1] = (short)f2bf(fa.y);
    b[t][2] = (short)f2bf(fa.z); b[t][3] = (short)f2bf(fa.w);
    b[t][4] = (short)f2bf(fb.x); b[t][5] = (short)f2bf(fb.y);
    b[t][6] = (short)f2bf(fb.z); b[t][7] = (short)f2bf(fb.w);
  }

  float acc[8] = {0.f, 0.f, 0.f, 0.f, 0.f, 0.f, 0.f, 0.f};
  for (int m = wave * 16; m < M; m += 128) {
    bf16x8 av = *(const bf16x8*)(Abf + (size_t)(m + r) * 32 + q * 8);
#pragma unroll
    for (int t = 0; t < 8; ++t) {
      f32x4 c = __builtin_amdgcn_mfma_f32_16x16x32_bf16(av, b[t], cinit, 0, 0, 0);
#pragma unroll
      for (int e = 0; e < 4; ++e)
        acc[t] += __int_as_float((int)fmaxf(c[e], CLAMPF));
    }
  }

#pragma unroll
  for (int t = 0; t < 8; ++t) {
    acc[t] += __shfl_xor(acc[t], 16);
    acc[t] += __shfl_xor(acc[t], 32);
  }
  float vlo = (q == 0) ? acc[0] : (q == 1) ? acc[1] : (q == 2) ? acc[2] : acc[3];
  float vhi = (q == 0) ? acc[4] : (q == 1) ? acc[5] : (q == 2) ? acc[6] : acc[7];

  __shared__ float rlo[8][64];
  __shared__ float rhi[8][64];
  rlo[wave][lane] = vlo;
  rhi[wave][lane] = vhi;
  __syncthreads();

  if (wave == 0) {
    float slo = 0.f, shi = 0.f;
#pragma unroll
    for (int w = 0; w < 8; ++w) { slo += rlo[w][lane]; shi += rhi[w][lane]; }
    slo = fmaxf(slo, 1e-38f);
    shi = fmaxf(shi, 1e-38f);
    float t = __logf(slo) + __logf(shi);
    t += __shfl_xor(t, 1);  t += __shfl_xor(t, 2);
    t += __shfl_xor(t, 4);  t += __shfl_xor(t, 8);
    t += __shfl_xor(t, 16); t += __shfl_xor(t, 32);
    if (lane == 0) atomicAdd(out, t / (float)J);
  }
}

extern "C" void kernel_launch(void* const* d_in, const int* in_sizes, int n_in,
                              void* d_out, int out_size, void* d_ws, size_t ws_size,
                              hipStream_t stream) {
  const float* mu  = (const float*)d_in[0];
  const float* z   = (const float*)d_in[1];
  const float* kp  = (const float*)d_in[2];
  const float* lck = (const float*)d_in[3];
  const float* lc0 = (const float*)d_in[4];
  const int M = in_sizes[0] / 32;   // 2048
  const int J = in_sizes[1] / 32;   // 65536 (= M * n_samples)
  float* out = (float*)d_out;

  unsigned short* Abf = (unsigned short*)d_ws;   // M*32*2 = 128 KB

  vmf_prep<<<(M * 8 + 255) / 256, 256, 0, stream>>>(mu, kp, lck, lc0, Abf, out, M);
  const int nblk = J / 128;  // 512 blocks, 8 waves each
  if (M == 2048)
    vmf_main<<<nblk, 512, 0, stream>>>(Abf, z, kp, out, J);
  else
    vmf_main_gen<<<nblk, 512, 0, stream>>>(Abf, z, kp, out, M, J);
}

// Round 10
// 79.994 us; speedup vs baseline: 7.5440x; 7.5440x over previous
//
#include <hip/hip_runtime.h>
#include <hip/hip_bf16.h>

// okl = log_C_kappa + kappa + mean_j log( sum_i exp(kappa*<mu_n_i,z_j> - kappa) )
//       - log(M) - log_C_zero
// M = 2048 components, J = 65536 sample columns, d = 32.
//
// Schraudolph epilogue (PROVEN R4/R8 form): A pre-scaled by kappa*log2e*2^23;
// MFMA C-operand holds (BIAS-S)*2^23 + MAGIC so the MFMA output c is the
// float whose int-truncation is the bit pattern of 2^(score-S+BIAS).
// Epilogue: fmaxf(c, 2^23) -> (int) -> __int_as_float -> add.
//
// R10 DIAGNOSTIC: NPASS=4 outer passes over the same rolled loop (acc exactly
// 4x, scaled by 0.25 before log). Pushes main to ~90us so it lands in the
// rocprof top-5 with VALID counters at its NATURAL VGPR/occupancy (~32 VGPR,
// no spill -- unlike R8's a[16] attempt).

typedef __attribute__((ext_vector_type(8))) short bf16x8;
typedef __attribute__((ext_vector_type(4))) float f32x4;

#define LOG2E 1.44269504088896340736
#define LN2 0.6931471805599453
#define BIAS 48.0
// 127*2^23 - D, D = 471400 (mean-log-centered linear-mantissa exp2)
#define MAGIC 1064881816.0
#define CLAMPF 8388608.0f   // 2^23: result exponent floor -> 2^-126, no wrap
#define NPASS 4             // DIAGNOSTIC work multiplier

static __device__ __forceinline__ unsigned short f2bf(float f) {
  unsigned int u = __float_as_uint(f);
  u += 0x7FFFu + ((u >> 16) & 1u);   // round-to-nearest-even
  return (unsigned short)(u >> 16);
}

// Kernel 1: Abf = bf16(kappa*log2e*2^23 * mu / ||mu||), 8 lanes per row.
// Thread 0 also writes out[0] = all-constant part of okl (main atomicAdds).
__global__ __launch_bounds__(256) void vmf_prep(const float* __restrict__ mu,
                                                const float* __restrict__ kp,
                                                const float* __restrict__ lck,
                                                const float* __restrict__ lc0,
                                                unsigned short* __restrict__ Abf,
                                                float* __restrict__ out, int M) {
  int tid = blockIdx.x * 256 + threadIdx.x;
  if (tid == 0) {
    out[0] = (float)((double)lck[0] + (double)kp[0] - BIAS * LN2 -
                     log((double)M) - (double)lc0[0]);
  }
  int row = tid >> 3;
  int sub = tid & 7;                  // 4 columns per lane
  if (row >= M) return;
  const float4 v = *(const float4*)(mu + (size_t)row * 32 + sub * 4);
  float ss = v.x * v.x + v.y * v.y + v.z * v.z + v.w * v.w;
  ss += __shfl_xor(ss, 1);
  ss += __shfl_xor(ss, 2);
  ss += __shfl_xor(ss, 4);            // full row norm within 8-lane group
  float sc = (float)((double)kp[0] * LOG2E * 8388608.0) / sqrtf(ss);
  ushort4 o;
  o.x = f2bf(v.x * sc); o.y = f2bf(v.y * sc);
  o.z = f2bf(v.z * sc); o.w = f2bf(v.w * sc);
  *(ushort4*)(Abf + (size_t)row * 32 + sub * 4) = o;
}

// Kernel 2: block = 128 cols (8 N-tiles) x 8 waves; wave covers M/8
// contiguous rows, rolled loop with wraparound prefetch (R4-proven body).
// NPASS outer passes (diagnostic). Block reduces to t_b, atomicAdds t_b/J.
__global__ __launch_bounds__(512) void vmf_main(const unsigned short* __restrict__ Abf,
                                                const float* __restrict__ z,
                                                const float* __restrict__ kp,
                                                float* __restrict__ out,
                                                int M, int J) {
  const int lane = threadIdx.x & 63;
  const int wave = threadIdx.x >> 6;   // 0..7
  const int r = lane & 15;
  const int q = lane >> 4;
  const float ci = (float)((BIAS - (double)kp[0] * LOG2E) * 8388608.0 + MAGIC);
  const f32x4 cinit = {ci, ci, ci, ci};
  const int colbase = blockIdx.x * 128;

  // Loop-invariant B fragments (8 tiles), fp32 -> bf16 on the fly (proven).
  bf16x8 b[8];
#pragma unroll
  for (int t = 0; t < 8; ++t) {
    const float* zp = z + (size_t)(colbase + t * 16 + r) * 32 + q * 8;
    float4 fa = *(const float4*)zp;
    float4 fb = *(const float4*)(zp + 4);
    b[t][0] = (short)f2bf(fa.x); b[t][1] = (short)f2bf(fa.y);
    b[t][2] = (short)f2bf(fa.z); b[t][3] = (short)f2bf(fa.w);
    b[t][4] = (short)f2bf(fb.x); b[t][5] = (short)f2bf(fb.y);
    b[t][6] = (short)f2bf(fb.z); b[t][7] = (short)f2bf(fb.w);
  }

  const int mchunk = M >> 3;           // 256 (power of 2)
  const unsigned short* ap = Abf + (size_t)(wave * mchunk + r) * 32 + q * 8;
  float acc[8] = {0.f, 0.f, 0.f, 0.f, 0.f, 0.f, 0.f, 0.f};
  for (int p = 0; p < NPASS; ++p) {
    bf16x8 av = *(const bf16x8*)ap;
    for (int m = 0; m < mchunk; m += 16) {
      const int mn = (m + 16) & (mchunk - 1);        // wraparound: branchless
      bf16x8 nxt = *(const bf16x8*)(ap + (size_t)mn * 32);
#pragma unroll
      for (int t = 0; t < 8; ++t) {
        f32x4 c = __builtin_amdgcn_mfma_f32_16x16x32_bf16(av, b[t], cinit, 0, 0, 0);
#pragma unroll
        for (int e = 0; e < 4; ++e) {
          float cf = fmaxf(c[e], CLAMPF);
          acc[t] += __int_as_float((int)cf);         // Schraudolph exp2
        }
      }
      av = nxt;
    }
  }

  // Sum the 4 row-quadrants per column (lanes l, l^16, l^32, l^48 share col).
#pragma unroll
  for (int t = 0; t < 8; ++t) {
    acc[t] += __shfl_xor(acc[t], 16);
    acc[t] += __shfl_xor(acc[t], 32);
  }
  float vlo = (q == 0) ? acc[0] : (q == 1) ? acc[1] : (q == 2) ? acc[2] : acc[3];
  float vhi = (q == 0) ? acc[4] : (q == 1) ? acc[5] : (q == 2) ? acc[6] : acc[7];

  __shared__ float rlo[8][64];
  __shared__ float rhi[8][64];
  rlo[wave][lane] = vlo;
  rhi[wave][lane] = vhi;
  __syncthreads();

  if (wave == 0) {
    float slo = 0.f, shi = 0.f;
#pragma unroll
    for (int w = 0; w < 8; ++w) { slo += rlo[w][lane]; shi += rhi[w][lane]; }
    slo = fmaxf(slo * (1.0f / NPASS), 1e-38f);   // undo diagnostic multiplier
    shi = fmaxf(shi * (1.0f / NPASS), 1e-38f);
    float t = __logf(slo) + __logf(shi);   // 2 columns' t_j for this lane
    t += __shfl_xor(t, 1);  t += __shfl_xor(t, 2);
    t += __shfl_xor(t, 4);  t += __shfl_xor(t, 8);
    t += __shfl_xor(t, 16); t += __shfl_xor(t, 32);
    if (lane == 0) atomicAdd(out, t / (float)J);
  }
}

extern "C" void kernel_launch(void* const* d_in, const int* in_sizes, int n_in,
                              void* d_out, int out_size, void* d_ws, size_t ws_size,
                              hipStream_t stream) {
  const float* mu  = (const float*)d_in[0];
  const float* z   = (const float*)d_in[1];
  const float* kp  = (const float*)d_in[2];
  const float* lck = (const float*)d_in[3];
  const float* lc0 = (const float*)d_in[4];
  const int M = in_sizes[0] / 32;   // 2048
  const int J = in_sizes[1] / 32;   // 65536 (= M * n_samples)
  float* out = (float*)d_out;

  unsigned short* Abf = (unsigned short*)d_ws;   // M*32*2 = 128 KB

  vmf_prep<<<(M * 8 + 255) / 256, 256, 0, stream>>>(mu, kp, lck, lc0, Abf, out, M);
  const int nblk = J / 128;  // 512 blocks, 8 waves each
  vmf_main<<<nblk, 512, 0, stream>>>(Abf, z, kp, out, M, J);
}